// Round 9
// baseline (233.932 us; speedup 1.0000x reference)
//
#include <hip/hip_runtime.h>
#include <hip/hip_bf16.h>
#include <float.h>

// MoE: n=4096 tokens, D=O=512, E=8, top-2, 3-layer ReLU MLP per expert.
// out[n] = p[n,0]*MLP_{e0}(x[n]) + p[n,1]*MLP_{e1}(x[n])   (slot-indexed probs quirk)
//
// Round-9: fused 3-layer kernel, 512 threads (8 waves, 2/SIMD) per 64-row tile.
//  - Wave tile 64 rows x 64 cols: acc[4][4]; per kc-step 4 A ds_reads + 4 B
//    global loads feed 16 MFMAs. Two waves/SIMD: one wave's MFMAs cover the
//    other's load stalls (block-internal TLP, no barriers in the K-loop).
//  - K-loop fully unrolled, branchless (prefetch (kc+1)&15, alternating b[kc&1]
//    register sets) -> one basic block, deep vmcnt pipelining.
//  - B in registers only (no LDS staging -> no DMA/ds_read alias drains).
//  - Scatter fused into gate: fixed 4096-row region per expert + cursor
//    atomics; 0xAA ws re-poison marks unwritten slots negative (pad detect).
//  - Expert->XCD affinity (e = bid&7); h in 64KB swizzled LDS; layer-3
//    scatters entry_w * relu(y) into out via f32 atomics.

#define NTOK   4096
#define DIM    512
#define NEXP   8
#define MATSZ  (DIM * DIM)         // f16 elems per matrix

typedef _Float16 half8 __attribute__((ext_vector_type(8)));
typedef float    f32x4 __attribute__((ext_vector_type(4)));

// ---- workspace layout (bytes) ----
#define META_OFF   0u          // int[64]: [8..15] per-expert cursors (= counts)
#define ETOK_OFF   4096u       // int[8*4096] = 128 KB
#define EW_OFF     135168u     // float[8*4096] = 128 KB
#define XH_OFF     266240u     // f16[4096*512] = 4 MB
#define WT_OFF     4460544u    // f16[24*512*512] = 12.6 MB packed

// col swizzle: element (row,col) stored at col ^ swz(row); multiples of 8 keep
// half8 runs contiguous and spread C/D row-quads across bank groups.
__device__ __forceinline__ int swz(int row) {
    return ((row & 7) << 3) ^ ((row & 8) << 1);
}

// ---------------- gate + convert_x + scatter + zero-out, fused ----------------
__global__ __launch_bounds__(256)
void gate_kernel(const float* __restrict__ x, const float* __restrict__ gw,
                 const float* __restrict__ gb,
                 _Float16* __restrict__ xh, int* __restrict__ meta,
                 int* __restrict__ entry_tok, float* __restrict__ entry_w,
                 float* __restrict__ out)
{
    int tid = threadIdx.x;
    int n = blockIdx.x * 4 + (tid >> 6);
    int lane = tid & 63;

    // zero this token's out row (fused_mlp accumulates atomically later)
    float4 z = {0.f, 0.f, 0.f, 0.f};
    float* op = out + (size_t)n * DIM + lane * 8;
    *(float4*)op = z;
    *(float4*)(op + 4) = z;

    const float* xr = x + (size_t)n * DIM + lane * 8;
    float4 v0 = *(const float4*)xr;
    float4 v1 = *(const float4*)(xr + 4);
    float xv[8] = {v0.x, v0.y, v0.z, v0.w, v1.x, v1.y, v1.z, v1.w};

    half8 h = { (_Float16)xv[0], (_Float16)xv[1], (_Float16)xv[2], (_Float16)xv[3],
                (_Float16)xv[4], (_Float16)xv[5], (_Float16)xv[6], (_Float16)xv[7] };
    *(half8*)(xh + (size_t)n * DIM + lane * 8) = h;

    float p[NEXP];
#pragma unroll
    for (int e = 0; e < NEXP; e++) p[e] = 0.f;
    const float* g = gw + (size_t)lane * 64;   // rows k = lane*8 .. lane*8+7
#pragma unroll
    for (int j = 0; j < 8; j++)
#pragma unroll
        for (int e = 0; e < NEXP; e++) p[e] += xv[j] * g[j * 8 + e];
#pragma unroll
    for (int e = 0; e < NEXP; e++) {
        float v = p[e];
        for (int off = 32; off; off >>= 1) v += __shfl_xor(v, off, 64);
        p[e] = v;
    }
    if (lane == 0) {
        float l[NEXP];
#pragma unroll
        for (int e = 0; e < NEXP; e++) l[e] = p[e] + gb[e];
        float m = l[0];
#pragma unroll
        for (int e = 1; e < NEXP; e++) m = fmaxf(m, l[e]);
        float ex[NEXP], s = 0.f;
#pragma unroll
        for (int e = 0; e < NEXP; e++) { ex[e] = expf(l[e] - m); s += ex[e]; }
        int e0 = 0; float m0 = l[0];
#pragma unroll
        for (int e = 1; e < NEXP; e++) if (l[e] > m0) { m0 = l[e]; e0 = e; }
        int e1 = -1; float m1 = -FLT_MAX;
#pragma unroll
        for (int e = 0; e < NEXP; e++) if (e != e0 && l[e] > m1) { m1 = l[e]; e1 = e; }
        float inv = 1.f / s;
        float w0 = ex[0] * inv, w1 = ex[1] * inv;  // slot-indexed probs (quirk)
        // direct scatter into fixed per-expert regions (order irrelevant)
        int p0 = (e0 << 12) + atomicAdd(&meta[8 + e0], 1);
        int p1 = (e1 << 12) + atomicAdd(&meta[8 + e1], 1);
        entry_tok[p0] = n;  entry_w[p0] = w0;
        entry_tok[p1] = n;  entry_w[p1] = w1;
    }
}

// ---------------- pack weights, LDS-staged coalesced ----------------
// W[mat][k][n] f32 -> packed f16: chunk (mat*512 + kc*32 + c16) holds
// B[16 cols][32 k] as one 1KB wave fragment: lane l -> col = c16*16 + (l&15),
// k = kc*32 + (l>>4)*8 + j.
__global__ __launch_bounds__(256)
void pack_w(const float* __restrict__ W1, const float* __restrict__ W2,
            const float* __restrict__ W3, _Float16* __restrict__ Wt)
{
    __shared__ float s[32 * 513];  // 32 k-rows x 512 cols, +1 pad
    int bid = blockIdx.x;          // 24 mats x 16 kc-chunks
    int mat = bid >> 4, kc = bid & 15;
    const float* src = ((mat < 8) ? W1 + (size_t)mat * MATSZ
                      : (mat < 16) ? W2 + (size_t)(mat - 8) * MATSZ
                                   : W3 + (size_t)(mat - 16) * MATSZ)
                     + (size_t)kc * 32 * DIM;
    int tid = threadIdx.x;
#pragma unroll
    for (int i = 0; i < 16; i++) {
        int idx = i * 1024 + tid * 4;
        int k = idx >> 9, c = idx & 511;
        float4 v = *(const float4*)(src + idx);
        float* d = &s[k * 513 + c];
        d[0] = v.x; d[1] = v.y; d[2] = v.z; d[3] = v.w;
    }
    __syncthreads();
    int w = tid >> 6, lane = tid & 63, l15 = lane & 15, l4 = lane >> 4;
#pragma unroll
    for (int i = 0; i < 8; i++) {
        int c16 = w * 8 + i;
        int col = c16 * 16 + l15;
        half8 h;
#pragma unroll
        for (int j = 0; j < 8; j++)
            h[j] = (_Float16)s[(l4 * 8 + j) * 513 + col];
        *(half8*)(Wt + (size_t)mat * MATSZ + (size_t)(kc * 32 + c16) * 512 + lane * 8) = h;
    }
}

// ---------------- fused 3-layer expert MLP: 512 thr, one block per tile ----------------
__global__ __launch_bounds__(512, 2)
void fused_mlp(const _Float16* __restrict__ xh, const _Float16* __restrict__ wt,
               const float* __restrict__ b1, const float* __restrict__ b2,
               const float* __restrict__ b3, float* __restrict__ out,
               const int* __restrict__ meta, const int* __restrict__ entry_tok,
               const float* __restrict__ entry_w)
{
    __shared__ _Float16 hbuf[64 * DIM];   // 64 KB, swizzled cols
    __shared__ int   rtok[64];
    __shared__ float rw[64];

    int bid = blockIdx.x;                 // grid = 8 * 64
    int e = bid & 7;                      // XCD affinity: blockIdx % 8 -> XCD
    int j = bid >> 3;
    int cnt = meta[8 + e];
    if (j >= ((cnt + 63) >> 6)) return;
    int row0 = (e << 12) + (j << 6);      // fixed 4096-row region per expert

    int tid = threadIdx.x;
    int w = tid >> 6, l = tid & 63;
    int l15 = l & 15, l4 = l >> 4;
    int colb = w * 64 + l15;              // wave w owns cols [w*64, w*64+64)

    if (tid < 64) {
        int t = entry_tok[row0 + tid];    // unwritten slots: 0xAA poison (<0)
        rtok[tid] = t;
        rw[tid]   = entry_w[row0 + tid];
    }
    __syncthreads();

    // fill hbuf with gathered x rows: 8 threads/row, 64 cols each
    {
        int row = tid >> 3;
        int c0 = (tid & 7) * 64;
        int tk = rtok[row]; if (tk < 0) tk = 0;   // garbage ok, dropped at epilogue
        const _Float16* src = xh + (size_t)tk * DIM + c0;
        int f = swz(row);
        _Float16* dst = hbuf + row * DIM;
#pragma unroll
        for (int q = 0; q < 8; q++) {
            half8 v = *(const half8*)(src + q * 8);
            *(half8*)(dst + ((c0 + q * 8) ^ f)) = v;
        }
    }
    __syncthreads();

    f32x4 acc[4][4];

    // one layer: A from hbuf, B reg-streamed; fully unrolled branchless pipeline
    auto run_layer = [&](const _Float16* __restrict__ Wp) {
#pragma unroll
        for (int rg = 0; rg < 4; rg++)
#pragma unroll
            for (int cg = 0; cg < 4; cg++) acc[rg][cg] = (f32x4){0.f, 0.f, 0.f, 0.f};
        // wave w uses chunks (kc*32 + w*4 + cg), each 512 f16 (1KB, lane*16B)
        const _Float16* wb = Wp + (size_t)(w * 4) * 512 + (size_t)l * 8;
        half8 b[2][4];
#pragma unroll
        for (int cg = 0; cg < 4; cg++)
            b[0][cg] = *(const half8*)(wb + (size_t)cg * 512);
#pragma unroll
        for (int kc = 0; kc < 16; kc++) {
            const int cur = kc & 1, nxt = cur ^ 1;
            const int kn = (kc + 1) & 15;          // wraps on last iter (harmless)
#pragma unroll
            for (int cg = 0; cg < 4; cg++)
                b[nxt][cg] = *(const half8*)(wb + (size_t)(kn * 32 + cg) * 512);
            int koff = kc * 32 + l4 * 8;
            half8 af[4];
#pragma unroll
            for (int rg = 0; rg < 4; rg++) {
                int row = rg * 16 + l15;
                af[rg] = *(const half8*)(hbuf + row * DIM + (koff ^ swz(row)));
            }
#pragma unroll
            for (int rg = 0; rg < 4; rg++)
#pragma unroll
                for (int cg = 0; cg < 4; cg++)
                    acc[rg][cg] = __builtin_amdgcn_mfma_f32_16x16x32_f16(af[rg], b[cur][cg], acc[rg][cg], 0, 0, 0);
        }
    };

    // relu(acc + bias) -> hbuf; C/D layout: col=l&15(+16cg), row=l4*4+r(+16rg)
    auto writeback = [&](const float* __restrict__ Bias) {
        float bs[4];
#pragma unroll
        for (int cg = 0; cg < 4; cg++) bs[cg] = Bias[e * DIM + colb + cg * 16];
        __syncthreads();                   // all waves' hbuf reads done
#pragma unroll
        for (int rg = 0; rg < 4; rg++)
#pragma unroll
            for (int r = 0; r < 4; r++) {
                int row = rg * 16 + l4 * 4 + r;
                int f = swz(row);
                _Float16* dst = hbuf + row * DIM;
#pragma unroll
                for (int cg = 0; cg < 4; cg++)
                    dst[(colb + cg * 16) ^ f] = (_Float16)fmaxf(acc[rg][cg][r] + bs[cg], 0.f);
            }
        __syncthreads();                   // next layer may read
    };

    run_layer(wt + (size_t)e * MATSZ);        writeback(b1);
    run_layer(wt + (size_t)(8 + e) * MATSZ);  writeback(b2);
    run_layer(wt + (size_t)(16 + e) * MATSZ);

    // layer-3 epilogue: out[tok] += entry_w * relu(acc + b3)
    float bs[4];
#pragma unroll
    for (int cg = 0; cg < 4; cg++) bs[cg] = b3[e * DIM + colb + cg * 16];
#pragma unroll
    for (int rg = 0; rg < 4; rg++)
#pragma unroll
        for (int r = 0; r < 4; r++) {
            int row = rg * 16 + l4 * 4 + r;
            int tok = rtok[row];
            if (tok >= 0) {
                float ww = rw[row];
                float* op = out + (size_t)tok * DIM + colb;
#pragma unroll
                for (int cg = 0; cg < 4; cg++) {
                    float v = fmaxf(acc[rg][cg][r] + bs[cg], 0.f);
                    atomicAdd(op + cg * 16, ww * v);
                }
            }
        }
}

extern "C" void kernel_launch(void* const* d_in, const int* in_sizes, int n_in,
                              void* d_out, int out_size, void* d_ws, size_t ws_size,
                              hipStream_t stream)
{
    const float* x      = (const float*)d_in[0];
    const float* gate_w = (const float*)d_in[1];
    const float* gate_b = (const float*)d_in[2];
    const float* w1     = (const float*)d_in[3];
    const float* b1     = (const float*)d_in[4];
    const float* w2     = (const float*)d_in[5];
    const float* b2     = (const float*)d_in[6];
    const float* w3     = (const float*)d_in[7];
    const float* b3     = (const float*)d_in[8];
    float* out = (float*)d_out;

    char* ws = (char*)d_ws;
    int*      meta      = (int*)(ws + META_OFF);
    int*      entry_tok = (int*)(ws + ETOK_OFF);
    float*    entry_w   = (float*)(ws + EW_OFF);
    _Float16* xh        = (_Float16*)(ws + XH_OFF);
    _Float16* wt        = (_Float16*)(ws + WT_OFF);

    hipMemsetAsync(meta, 0, 256, stream);

    gate_kernel<<<NTOK / 4, 256, 0, stream>>>(x, gate_w, gate_b, xh, meta,
                                              entry_tok, entry_w, out);
    pack_w<<<24 * 16, 256, 0, stream>>>(w1, w2, w3, wt);

    fused_mlp<<<NEXP * 64, 512, 0, stream>>>(xh, wt, b1, b2, b3, out,
                                             meta, entry_tok, entry_w);
}

// Round 10
// 161.097 us; speedup vs baseline: 1.4521x; 1.4521x over previous
//
#include <hip/hip_runtime.h>
#include <hip/hip_bf16.h>
#include <float.h>

// MoE: n=4096 tokens, D=O=512, E=8, top-2, 3-layer ReLU MLP per expert.
// out[n] = p[n,0]*MLP_{e0}(x[n]) + p[n,1]*MLP_{e1}(x[n])   (slot-indexed probs quirk)
//
// Round-10: round-9 structure, but scatter de-fused from gate (r9's 8192
// serialized atomic-with-return on one cache line cost 104 us). Scatter is a
// separate 16-block kernel with wave-aggregated ballot claims (~256 atomics).
//  - fused_mlp unchanged from r9: 512 thr (2 waves/SIMD), 64x64 wave tile,
//    acc[4][4], branchless unrolled K-loop, B reg-streamed, fixed per-expert
//    entry regions (e<<12), XCD affinity e = bid&7, h in 64KB swizzled LDS,
//    layer-3 scatters entry_w * relu(y) via f32 atomics.

#define NTOK   4096
#define DIM    512
#define NEXP   8
#define MATSZ  (DIM * DIM)         // f16 elems per matrix

typedef _Float16 half8 __attribute__((ext_vector_type(8)));
typedef float    f32x4 __attribute__((ext_vector_type(4)));

// ---- workspace layout (bytes) ----
#define META_OFF   0u          // int[64]: [8..15] per-expert cursors (= counts)
#define TOPE_OFF   1024u       // int[8192]
#define TOPW_OFF   33792u      // float[8192]
#define ETOK_OFF   66560u      // int[8*4096] = 128 KB
#define EW_OFF     197632u     // float[8*4096] = 128 KB
#define XH_OFF     328704u     // f16[4096*512] = 4 MB
#define WT_OFF     4523008u    // f16[24*512*512] = 12.6 MB packed

// col swizzle: element (row,col) stored at col ^ swz(row); multiples of 8 keep
// half8 runs contiguous and spread C/D row-quads across bank groups.
__device__ __forceinline__ int swz(int row) {
    return ((row & 7) << 3) ^ ((row & 8) << 1);
}

// ---------------- gate + convert_x + zero-out (NO atomics) ----------------
__global__ __launch_bounds__(256)
void gate_kernel(const float* __restrict__ x, const float* __restrict__ gw,
                 const float* __restrict__ gb,
                 int* __restrict__ top_e, float* __restrict__ top_w,
                 _Float16* __restrict__ xh, float* __restrict__ out)
{
    int tid = threadIdx.x;
    int n = blockIdx.x * 4 + (tid >> 6);
    int lane = tid & 63;

    // zero this token's out row (fused_mlp accumulates atomically later)
    float4 z = {0.f, 0.f, 0.f, 0.f};
    float* op = out + (size_t)n * DIM + lane * 8;
    *(float4*)op = z;
    *(float4*)(op + 4) = z;

    const float* xr = x + (size_t)n * DIM + lane * 8;
    float4 v0 = *(const float4*)xr;
    float4 v1 = *(const float4*)(xr + 4);
    float xv[8] = {v0.x, v0.y, v0.z, v0.w, v1.x, v1.y, v1.z, v1.w};

    half8 h = { (_Float16)xv[0], (_Float16)xv[1], (_Float16)xv[2], (_Float16)xv[3],
                (_Float16)xv[4], (_Float16)xv[5], (_Float16)xv[6], (_Float16)xv[7] };
    *(half8*)(xh + (size_t)n * DIM + lane * 8) = h;

    float p[NEXP];
#pragma unroll
    for (int e = 0; e < NEXP; e++) p[e] = 0.f;
    const float* g = gw + (size_t)lane * 64;   // rows k = lane*8 .. lane*8+7
#pragma unroll
    for (int j = 0; j < 8; j++)
#pragma unroll
        for (int e = 0; e < NEXP; e++) p[e] += xv[j] * g[j * 8 + e];
#pragma unroll
    for (int e = 0; e < NEXP; e++) {
        float v = p[e];
        for (int off = 32; off; off >>= 1) v += __shfl_xor(v, off, 64);
        p[e] = v;
    }
    if (lane == 0) {
        float l[NEXP];
#pragma unroll
        for (int e = 0; e < NEXP; e++) l[e] = p[e] + gb[e];
        float m = l[0];
#pragma unroll
        for (int e = 1; e < NEXP; e++) m = fmaxf(m, l[e]);
        float ex[NEXP], s = 0.f;
#pragma unroll
        for (int e = 0; e < NEXP; e++) { ex[e] = expf(l[e] - m); s += ex[e]; }
        int e0 = 0; float m0 = l[0];
#pragma unroll
        for (int e = 1; e < NEXP; e++) if (l[e] > m0) { m0 = l[e]; e0 = e; }
        int e1 = -1; float m1 = -FLT_MAX;
#pragma unroll
        for (int e = 0; e < NEXP; e++) if (e != e0 && l[e] > m1) { m1 = l[e]; e1 = e; }
        float inv = 1.f / s;
        top_e[2 * n + 0] = e0;
        top_e[2 * n + 1] = e1;
        top_w[2 * n + 0] = ex[0] * inv;   // slot-indexed probs (reference quirk)
        top_w[2 * n + 1] = ex[1] * inv;
    }
}

// ---------------- scatter: wave-aggregated claims into fixed regions ----------------
__global__ __launch_bounds__(256)
void scatter_kernel(const int* __restrict__ top_e, const float* __restrict__ top_w,
                    int* __restrict__ meta, int* __restrict__ entry_tok,
                    float* __restrict__ entry_w)
{
    int n = blockIdx.x * 256 + threadIdx.x;
    int lane = threadIdx.x & 63;
#pragma unroll
    for (int j = 0; j < 2; j++) {
        int e = top_e[2 * n + j];
        float ww = top_w[2 * n + j];
        int pos = 0;
        for (int ex = 0; ex < NEXP; ex++) {
            unsigned long long m = __ballot(e == ex);
            if (e == ex) {
                int leader = __ffsll(m) - 1;
                int base = 0;
                if (lane == leader) base = atomicAdd(&meta[8 + ex], __popcll(m));
                base = __shfl(base, leader, 64);
                pos = (ex << 12) + base + __popcll(m & ((1ull << lane) - 1ull));
            }
        }
        entry_tok[pos] = n;
        entry_w[pos] = ww;
    }
}

// ---------------- pack weights, LDS-staged coalesced ----------------
// W[mat][k][n] f32 -> packed f16: chunk (mat*512 + kc*32 + c16) holds
// B[16 cols][32 k] as one 1KB wave fragment: lane l -> col = c16*16 + (l&15),
// k = kc*32 + (l>>4)*8 + j.
__global__ __launch_bounds__(256)
void pack_w(const float* __restrict__ W1, const float* __restrict__ W2,
            const float* __restrict__ W3, _Float16* __restrict__ Wt)
{
    __shared__ float s[32 * 513];  // 32 k-rows x 512 cols, +1 pad
    int bid = blockIdx.x;          // 24 mats x 16 kc-chunks
    int mat = bid >> 4, kc = bid & 15;
    const float* src = ((mat < 8) ? W1 + (size_t)mat * MATSZ
                      : (mat < 16) ? W2 + (size_t)(mat - 8) * MATSZ
                                   : W3 + (size_t)(mat - 16) * MATSZ)
                     + (size_t)kc * 32 * DIM;
    int tid = threadIdx.x;
#pragma unroll
    for (int i = 0; i < 16; i++) {
        int idx = i * 1024 + tid * 4;
        int k = idx >> 9, c = idx & 511;
        float4 v = *(const float4*)(src + idx);
        float* d = &s[k * 513 + c];
        d[0] = v.x; d[1] = v.y; d[2] = v.z; d[3] = v.w;
    }
    __syncthreads();
    int w = tid >> 6, lane = tid & 63, l15 = lane & 15, l4 = lane >> 4;
#pragma unroll
    for (int i = 0; i < 8; i++) {
        int c16 = w * 8 + i;
        int col = c16 * 16 + l15;
        half8 h;
#pragma unroll
        for (int j = 0; j < 8; j++)
            h[j] = (_Float16)s[(l4 * 8 + j) * 513 + col];
        *(half8*)(Wt + (size_t)mat * MATSZ + (size_t)(kc * 32 + c16) * 512 + lane * 8) = h;
    }
}

// ---------------- fused 3-layer expert MLP: 512 thr, one block per tile ----------------
__global__ __launch_bounds__(512, 2)
void fused_mlp(const _Float16* __restrict__ xh, const _Float16* __restrict__ wt,
               const float* __restrict__ b1, const float* __restrict__ b2,
               const float* __restrict__ b3, float* __restrict__ out,
               const int* __restrict__ meta, const int* __restrict__ entry_tok,
               const float* __restrict__ entry_w)
{
    __shared__ _Float16 hbuf[64 * DIM];   // 64 KB, swizzled cols
    __shared__ int   rtok[64];
    __shared__ float rw[64];

    int bid = blockIdx.x;                 // grid = 8 * 64
    int e = bid & 7;                      // XCD affinity: blockIdx % 8 -> XCD
    int j = bid >> 3;
    int cnt = meta[8 + e];
    if (j >= ((cnt + 63) >> 6)) return;
    int row0 = (e << 12) + (j << 6);      // fixed 4096-row region per expert

    int tid = threadIdx.x;
    int w = tid >> 6, l = tid & 63;
    int l15 = l & 15, l4 = l >> 4;
    int colb = w * 64 + l15;              // wave w owns cols [w*64, w*64+64)

    if (tid < 64) {
        int t = entry_tok[row0 + tid];    // unwritten slots: 0xAA poison (<0)
        rtok[tid] = t;
        rw[tid]   = entry_w[row0 + tid];
    }
    __syncthreads();

    // fill hbuf with gathered x rows: 8 threads/row, 64 cols each
    {
        int row = tid >> 3;
        int c0 = (tid & 7) * 64;
        int tk = rtok[row]; if (tk < 0) tk = 0;   // garbage ok, dropped at epilogue
        const _Float16* src = xh + (size_t)tk * DIM + c0;
        int f = swz(row);
        _Float16* dst = hbuf + row * DIM;
#pragma unroll
        for (int q = 0; q < 8; q++) {
            half8 v = *(const half8*)(src + q * 8);
            *(half8*)(dst + ((c0 + q * 8) ^ f)) = v;
        }
    }
    __syncthreads();

    f32x4 acc[4][4];

    // one layer: A from hbuf, B reg-streamed; fully unrolled branchless pipeline
    auto run_layer = [&](const _Float16* __restrict__ Wp) {
#pragma unroll
        for (int rg = 0; rg < 4; rg++)
#pragma unroll
            for (int cg = 0; cg < 4; cg++) acc[rg][cg] = (f32x4){0.f, 0.f, 0.f, 0.f};
        // wave w uses chunks (kc*32 + w*4 + cg), each 512 f16 (1KB, lane*16B)
        const _Float16* wb = Wp + (size_t)(w * 4) * 512 + (size_t)l * 8;
        half8 b[2][4];
#pragma unroll
        for (int cg = 0; cg < 4; cg++)
            b[0][cg] = *(const half8*)(wb + (size_t)cg * 512);
#pragma unroll
        for (int kc = 0; kc < 16; kc++) {
            const int cur = kc & 1, nxt = cur ^ 1;
            const int kn = (kc + 1) & 15;          // wraps on last iter (harmless)
#pragma unroll
            for (int cg = 0; cg < 4; cg++)
                b[nxt][cg] = *(const half8*)(wb + (size_t)(kn * 32 + cg) * 512);
            int koff = kc * 32 + l4 * 8;
            half8 af[4];
#pragma unroll
            for (int rg = 0; rg < 4; rg++) {
                int row = rg * 16 + l15;
                af[rg] = *(const half8*)(hbuf + row * DIM + (koff ^ swz(row)));
            }
#pragma unroll
            for (int rg = 0; rg < 4; rg++)
#pragma unroll
                for (int cg = 0; cg < 4; cg++)
                    acc[rg][cg] = __builtin_amdgcn_mfma_f32_16x16x32_f16(af[rg], b[cur][cg], acc[rg][cg], 0, 0, 0);
        }
    };

    // relu(acc + bias) -> hbuf; C/D layout: col=l&15(+16cg), row=l4*4+r(+16rg)
    auto writeback = [&](const float* __restrict__ Bias) {
        float bs[4];
#pragma unroll
        for (int cg = 0; cg < 4; cg++) bs[cg] = Bias[e * DIM + colb + cg * 16];
        __syncthreads();                   // all waves' hbuf reads done
#pragma unroll
        for (int rg = 0; rg < 4; rg++)
#pragma unroll
            for (int r = 0; r < 4; r++) {
                int row = rg * 16 + l4 * 4 + r;
                int f = swz(row);
                _Float16* dst = hbuf + row * DIM;
#pragma unroll
                for (int cg = 0; cg < 4; cg++)
                    dst[(colb + cg * 16) ^ f] = (_Float16)fmaxf(acc[rg][cg][r] + bs[cg], 0.f);
            }
        __syncthreads();                   // next layer may read
    };

    run_layer(wt + (size_t)e * MATSZ);        writeback(b1);
    run_layer(wt + (size_t)(8 + e) * MATSZ);  writeback(b2);
    run_layer(wt + (size_t)(16 + e) * MATSZ);

    // layer-3 epilogue: out[tok] += entry_w * relu(acc + b3)
    float bs[4];
#pragma unroll
    for (int cg = 0; cg < 4; cg++) bs[cg] = b3[e * DIM + colb + cg * 16];
#pragma unroll
    for (int rg = 0; rg < 4; rg++)
#pragma unroll
        for (int r = 0; r < 4; r++) {
            int row = rg * 16 + l4 * 4 + r;
            int tok = rtok[row];
            if (tok >= 0) {
                float ww = rw[row];
                float* op = out + (size_t)tok * DIM + colb;
#pragma unroll
                for (int cg = 0; cg < 4; cg++) {
                    float v = fmaxf(acc[rg][cg][r] + bs[cg], 0.f);
                    atomicAdd(op + cg * 16, ww * v);
                }
            }
        }
}

extern "C" void kernel_launch(void* const* d_in, const int* in_sizes, int n_in,
                              void* d_out, int out_size, void* d_ws, size_t ws_size,
                              hipStream_t stream)
{
    const float* x      = (const float*)d_in[0];
    const float* gate_w = (const float*)d_in[1];
    const float* gate_b = (const float*)d_in[2];
    const float* w1     = (const float*)d_in[3];
    const float* b1     = (const float*)d_in[4];
    const float* w2     = (const float*)d_in[5];
    const float* b2     = (const float*)d_in[6];
    const float* w3     = (const float*)d_in[7];
    const float* b3     = (const float*)d_in[8];
    float* out = (float*)d_out;

    char* ws = (char*)d_ws;
    int*      meta      = (int*)(ws + META_OFF);
    int*      top_e     = (int*)(ws + TOPE_OFF);
    float*    top_w     = (float*)(ws + TOPW_OFF);
    int*      entry_tok = (int*)(ws + ETOK_OFF);
    float*    entry_w   = (float*)(ws + EW_OFF);
    _Float16* xh        = (_Float16*)(ws + XH_OFF);
    _Float16* wt        = (_Float16*)(ws + WT_OFF);

    hipMemsetAsync(meta, 0, 256, stream);

    gate_kernel<<<NTOK / 4, 256, 0, stream>>>(x, gate_w, gate_b, top_e, top_w, xh, out);
    scatter_kernel<<<NTOK / 256, 256, 0, stream>>>(top_e, top_w, meta, entry_tok, entry_w);
    pack_w<<<24 * 16, 256, 0, stream>>>(w1, w2, w3, wt);

    fused_mlp<<<NEXP * 64, 512, 0, stream>>>(xh, wt, b1, b2, b3, out,
                                             meta, entry_tok, entry_w);
}